// Round 1
// baseline (360.675 us; speedup 1.0000x reference)
//
#include <hip/hip_runtime.h>

// Residual_feature: three chained depthwise convs on (64,3,512,512) fp32.
//   edge     = conv(x, K1)        K1 inner 3x3 = 8*delta - m3^T m3, m3=[1,-2,1]
//   texture  = conv(edge, K2)     K2 = -(l^T l) - 2*(m^T m), l=[1,-2,2,-2,1], m=[0,1,-2,1,0]
//   residual = conv(texture, K3)  K3 = horizontal [1,-2,1]
// Per-stage zero padding == zero intermediates outside the image; implemented
// exactly via lane-boundary zeroing (wave spans the full 512-col row) and
// row-index guards.

#define H 512
#define W 512
#define RS 32          // output rows per wave-strip
#define STRIPS (H/RS)  // 16

__device__ __forceinline__ void load_row(const float* __restrict__ xp, int gr, int cb,
                                         int lane, float v[8], float& vl, float& vh) {
    if (gr >= 0 && gr < H) {
        const float4* p = (const float4*)(xp + gr * W + cb);
        float4 a = p[0], b = p[1];
        v[0] = a.x; v[1] = a.y; v[2] = a.z; v[3] = a.w;
        v[4] = b.x; v[5] = b.y; v[6] = b.z; v[7] = b.w;
    } else {
        #pragma unroll
        for (int j = 0; j < 8; ++j) v[j] = 0.f;
    }
    vl = __shfl_up(v[7], 1, 64);
    vh = __shfl_down(v[0], 1, 64);
    if (lane == 0)  vl = 0.f;   // x zero-pad at col -1
    if (lane == 63) vh = 0.f;   // x zero-pad at col 512
}

__global__ __launch_bounds__(256, 3)
void resid_kernel(const float* __restrict__ x, float* __restrict__ out) {
    const int lane  = threadIdx.x & 63;
    const int wid   = (blockIdx.x << 2) | (threadIdx.x >> 6);
    const int plane = wid >> 4;            // wid / STRIPS
    const int strip = wid & (STRIPS - 1);
    const int r0    = strip * RS;
    const int cb    = lane << 3;           // 8 contiguous cols per lane

    const float* __restrict__ xp = x + (size_t)plane * (H * W);
    float* __restrict__ op = out + (size_t)plane * (H * W);

    // rolling x window: rows er-1 (xa), er (xb), er+1 (xc), + L/R halo scalars
    float xa[8], xb[8], xc[8];
    float xal, xah, xbl, xbh, xcl, xch;
    // rolling windows of horizontal-filtered edge rows:
    //   L = l * edge (5-tap), M = m * edge (3-tap)
    float Lw[5][8], Mw[3][8];

    #pragma unroll
    for (int k = 0; k < 5; ++k)
        #pragma unroll
        for (int j = 0; j < 8; ++j) Lw[k][j] = 0.f;
    #pragma unroll
    for (int k = 0; k < 3; ++k)
        #pragma unroll
        for (int j = 0; j < 8; ++j) Mw[k][j] = 0.f;

    load_row(xp, r0 - 3, cb, lane, xa, xal, xah);
    load_row(xp, r0 - 2, cb, lane, xb, xbl, xbh);

    // er = edge row produced this iteration; output row p = er-2 emitted when ready
    for (int er = r0 - 2; er <= r0 + RS + 1; ++er) {
        load_row(xp, er + 1, cb, lane, xc, xcl, xch);

        float Lr[8], Mr[8];
        if (er >= 0 && er < H) {
            // ---- edge row er (K1 inner 3x3), s = x[er-1] + x[er+1]
            float s[8], e[8];
            #pragma unroll
            for (int j = 0; j < 8; ++j) s[j] = xa[j] + xc[j];
            float sl = xal + xcl, sh = xah + xch;
            #pragma unroll
            for (int j = 0; j < 8; ++j) {
                float sm = ((j == 0) ? sl  : s[j-1]) + ((j == 7) ? sh  : s[j+1]);
                float xm = ((j == 0) ? xbl : xb[j-1]) + ((j == 7) ? xbh : xb[j+1]);
                e[j] = 2.f*s[j] - sm + 2.f*xm + 4.f*xb[j];
            }
            // ---- horizontal passes: L = [1,-2,2,-2,1]*e, M = [1,-2,1]*e
            float el1 = __shfl_up(e[7], 1, 64);
            float el2 = __shfl_up(e[6], 1, 64);
            float eh1 = __shfl_down(e[0], 1, 64);
            float eh2 = __shfl_down(e[1], 1, 64);
            if (lane == 0)  { el1 = 0.f; el2 = 0.f; }   // edge==0 outside image cols
            if (lane == 63) { eh1 = 0.f; eh2 = 0.f; }
            #pragma unroll
            for (int j = 0; j < 8; ++j) {
                float em1 = (j == 0) ? el1 : e[j-1];
                float ep1 = (j == 7) ? eh1 : e[j+1];
                float em2 = (j == 0) ? el2 : ((j == 1) ? el1 : e[j-2]);
                float ep2 = (j == 7) ? eh2 : ((j == 6) ? eh1 : e[j+2]);
                float pj = em1 + ep1;
                float qj = em2 + ep2;
                Lr[j] = qj - 2.f*pj + 2.f*e[j];
                Mr[j] = pj - 2.f*e[j];
            }
        } else {
            // edge row outside image -> zero intermediate (staged padding semantics)
            #pragma unroll
            for (int j = 0; j < 8; ++j) { Lr[j] = 0.f; Mr[j] = 0.f; }
        }

        // push L (window holds rows er-4..er after push)
        #pragma unroll
        for (int j = 0; j < 8; ++j) {
            Lw[0][j] = Lw[1][j]; Lw[1][j] = Lw[2][j];
            Lw[2][j] = Lw[3][j]; Lw[3][j] = Lw[4][j];
            Lw[4][j] = Lr[j];
        }

        if (er >= r0 + 2) {
            const int orow = er - 2;
            // ---- vertical combine: texture = -(l_v . L) - 2*(m_v . M)
            // Lw[k] = L row orow-2+k ; Mw[k] (pre-push) = M row orow-1+k
            float t[8];
            #pragma unroll
            for (int j = 0; j < 8; ++j) {
                float lsum = Lw[0][j] - 2.f*Lw[1][j] + 2.f*Lw[2][j] - 2.f*Lw[3][j] + Lw[4][j];
                float msum = Mw[0][j] - 2.f*Mw[1][j] + Mw[2][j];
                t[j] = -lsum - 2.f*msum;
            }
            // ---- residual = [1,-2,1] * texture (horizontal), texture==0 outside cols
            float tl = __shfl_up(t[7], 1, 64);
            float th = __shfl_down(t[0], 1, 64);
            if (lane == 0)  tl = 0.f;
            if (lane == 63) th = 0.f;
            float r[8];
            #pragma unroll
            for (int j = 0; j < 8; ++j) {
                float rm = (j == 0) ? tl : t[j-1];
                float rp = (j == 7) ? th : t[j+1];
                r[j] = rm + rp - 2.f*t[j];
            }
            float4 o0 = make_float4(r[0], r[1], r[2], r[3]);
            float4 o1 = make_float4(r[4], r[5], r[6], r[7]);
            float* dst = op + orow * W + cb;
            *(float4*)(dst)     = o0;
            *(float4*)(dst + 4) = o1;
        }

        // push M (after emit: window must lag by one row)
        #pragma unroll
        for (int j = 0; j < 8; ++j) {
            Mw[0][j] = Mw[1][j]; Mw[1][j] = Mw[2][j]; Mw[2][j] = Mr[j];
        }
        // rotate x window
        #pragma unroll
        for (int j = 0; j < 8; ++j) { xa[j] = xb[j]; xb[j] = xc[j]; }
        xal = xbl; xah = xbh; xbl = xcl; xbh = xch;
    }
}

extern "C" void kernel_launch(void* const* d_in, const int* in_sizes, int n_in,
                              void* d_out, int out_size, void* d_ws, size_t ws_size,
                              hipStream_t stream) {
    const float* x = (const float*)d_in[0];
    float* out = (float*)d_out;
    // 192 planes * 16 strips = 3072 waves / 4 waves per block = 768 blocks (3/CU)
    resid_kernel<<<dim3(768), dim3(256), 0, stream>>>(x, out);
}